// Round 3
// baseline (44.581 us; speedup 1.0000x reference)
//
#include <hip/hip_runtime.h>

// IAF multi-spike scan, B=8, T=128, C*H*W=32768, threshold=subtract=1.
// Layout [B, T, CHW]: idx(b,t,n) = (b*T + t)*CHW + n.
//
// Closed form (valid for NON-NEGATIVE inputs, which spike counts are):
//   sub_t = floor(cum_t)  =>  s_t = floor(cum_t) - floor(cum_{t-1})
// (residual cum_t - sub_t stays in [0,1); floor(int + y) = int + floor(y))
// This makes the T-scan a prefix sum, so T can be chunked for parallelism.
//
// Structure: thread = (quad of 4 neurons, chunk of 16 timesteps).
//   Phase 1: load 16 float4 of own chunk into regs, compute chunk sum.
//   Phase 2: LDS exchange -> exclusive prefix of chunk sums per quad.
//   Phase 3: cum = prefix; emit s = floor(cum_t) - floor(cum_{t-1}).
//
// R3 change: non-temporal output stores (write-once stream) so the output
// doesn't evict the input from L2/L3 -> input stays L3-resident across
// graph replays -> HBM traffic ~= writes only.

typedef float f32x4 __attribute__((ext_vector_type(4)));

constexpr int kT     = 128;
constexpr int kQPB   = 32 * 32 * 32 / 4;   // 8192 float4-quads per (b,t) slice
constexpr int kNC    = 8;                  // chunks over T
constexpr int kCL    = kT / kNC;           // 16 timesteps per chunk
constexpr int kQPBlk = 32;                 // quads per block (256 thr = 32q x 8c)

__global__ __launch_bounds__(256) void iaf_scan_kernel(
    const f32x4* __restrict__ in, f32x4* __restrict__ out) {
  __shared__ f32x4 csums[kNC][kQPBlk];

  const int tid = threadIdx.x;
  const int ql  = tid & (kQPBlk - 1);      // quad within block
  const int c   = tid >> 5;                // chunk index

  const int gq = blockIdx.x * kQPBlk + ql; // global quad in [0, 65536)
  const int b  = gq >> 13;                 // / 8192
  const int q  = gq & (kQPB - 1);          // % 8192

  const size_t base = (size_t)b * kT * kQPB + q + (size_t)c * kCL * kQPB;
  const f32x4* __restrict__ ip = in + base;
  f32x4* __restrict__ op = out + base;

  // Phase 1: 16 independent loads in flight, then chunk sum.
  f32x4 x[kCL];
#pragma unroll
  for (int i = 0; i < kCL; ++i) x[i] = ip[(size_t)i * kQPB];

  f32x4 cs = (f32x4)(0.f);
#pragma unroll
  for (int i = 0; i < kCL; ++i) cs += x[i];

  // Phase 2: exclusive prefix of chunk sums for this quad.
  csums[c][ql] = cs;
  __syncthreads();

  f32x4 cum = (f32x4)(0.f);
  for (int cc = 0; cc < c; ++cc) cum += csums[cc][ql];

  // Phase 3: emit floor-diffs with non-temporal stores.
  f32x4 pf;
  pf.x = floorf(cum.x); pf.y = floorf(cum.y);
  pf.z = floorf(cum.z); pf.w = floorf(cum.w);

#pragma unroll
  for (int i = 0; i < kCL; ++i) {
    f32x4 s;
    cum += x[i];
    { float nf = floorf(cum.x); s.x = nf - pf.x; pf.x = nf; }
    { float nf = floorf(cum.y); s.y = nf - pf.y; pf.y = nf; }
    { float nf = floorf(cum.z); s.z = nf - pf.z; pf.z = nf; }
    { float nf = floorf(cum.w); s.w = nf - pf.w; pf.w = nf; }
    __builtin_nontemporal_store(s, &op[(size_t)i * kQPB]);
  }
}

extern "C" void kernel_launch(void* const* d_in, const int* in_sizes, int n_in,
                              void* d_out, int out_size, void* d_ws, size_t ws_size,
                              hipStream_t stream) {
  (void)in_sizes; (void)n_in; (void)d_ws; (void)ws_size; (void)out_size;
  const f32x4* in = (const f32x4*)d_in[0];
  f32x4* out = (f32x4*)d_out;

  const int total_quads = 8 * kQPB;                  // 65536
  const int grid = total_quads / kQPBlk;             // 2048 blocks
  iaf_scan_kernel<<<grid, 256, 0, stream>>>(in, out);
}